// Round 7
// baseline (119.658 us; speedup 1.0000x reference)
//
#include <hip/hip_runtime.h>
#include <hip/hip_bf16.h>
#include <stdint.h>

// BatchHardTripletLoss: N=4096, D=512, C=128, margin=0.3
// hardest-pos = min gram (same label, j!=i), hardest-neg = max gram (diff
// label); dist=sqrt(2-2g) monotone. Triangular 128x128 tiles (528 blocks).
// Fragment-major packed layout (R6): one wave's 16-row x 32-k MFMA fragment
// group is one coalesced 16B/lane load; gram K-loop has no LDS, no barriers.
// R7: (1) tl_norm rewritten block-per-16-rows with LDS transpose so packed
// stores are fully coalesced (R6 stored scattered 8B chunks); (2) tl_final
// fused into tl_gram via completion counter (fence+atomic reads, proven R3).

#define NROW 4096
#define DIM  512
#define MARGIN 0.3f
#define BT 128
#define KITERS 16                          // K-chunks of 32
#define NTILE (NROW / BT)                  // 32
#define NPAIR (NTILE * (NTILE + 1) / 2)    // 528
#define POS_INIT 0xFFFFFFFFu
#define NEG_INIT 0u

typedef __attribute__((ext_vector_type(8))) __bf16 bf16x8;
typedef __attribute__((ext_vector_type(4))) float  f32x4;

__device__ __forceinline__ unsigned enc(float f) {
    unsigned u = __float_as_uint(f);
    return (u & 0x80000000u) ? ~u : (u | 0x80000000u);
}
__device__ __forceinline__ float dec(unsigned e) {
    return (e & 0x80000000u) ? __uint_as_float(e & 0x7fffffffu)
                             : __uint_as_float(~e);
}
__device__ __forceinline__ unsigned short f2bf(float f) {
    __hip_bfloat16 h = __float2bfloat16(f);
    return *reinterpret_cast<unsigned short*>(&h);
}

// ---- kernel 1: L2-normalize 16 rows/block -> packed bf16, coalesced ----
// Packed layout (matches gram reader): group g = row/16 is a 16 KB block;
// byte(row,k) = g*16384 + (k/32)*1024 + (((k>>3)&3)*16 + row%16)*16 + (k&7)*2
#define LROW 520   // LDS row stride in bf16 elems (1040 B: breaks 16-way bank collision)
__global__ void tl_norm(const float* __restrict__ E,
                        char* __restrict__ Epack,
                        unsigned* __restrict__ posArr,
                        unsigned* __restrict__ negArr,
                        unsigned* __restrict__ doneCnt) {
    __shared__ __align__(16) unsigned short sm[16 * LROW]; // 16.6 KB
    const int tid  = threadIdx.x;
    const int wave = tid >> 6;
    const int lane = tid & 63;

    if (blockIdx.x < 16) {
        int t = blockIdx.x * 256 + tid;    // covers 4096
        posArr[t] = POS_INIT;
        negArr[t] = NEG_INIT;
        if (t == 0) *doneCnt = 0;
    }

    const int rowBase = blockIdx.x * 16;   // 256 blocks x 16 rows

    // each wave normalizes 4 rows (coalesced float4 reads), stashes bf16 in LDS
    #pragma unroll
    for (int rr = 0; rr < 4; rr++) {
        const int r   = wave * 4 + rr;               // local row 0..15
        const int row = rowBase + r;
        const float4* src = (const float4*)(E + (size_t)row * DIM);
        float4 v0 = src[lane];          // k = 4*lane .. +3
        float4 v1 = src[lane + 64];     // k = 256 + 4*lane .. +3
        float ss = v0.x*v0.x + v0.y*v0.y + v0.z*v0.z + v0.w*v0.w
                 + v1.x*v1.x + v1.y*v1.y + v1.z*v1.z + v1.w*v1.w;
        #pragma unroll
        for (int m = 32; m >= 1; m >>= 1) ss += __shfl_xor(ss, m);
        float inv = 1.0f / fmaxf(sqrtf(ss), 1e-12f);

        ushort4 o0, o1;
        o0.x = f2bf(v0.x * inv); o0.y = f2bf(v0.y * inv);
        o0.z = f2bf(v0.z * inv); o0.w = f2bf(v0.w * inv);
        o1.x = f2bf(v1.x * inv); o1.y = f2bf(v1.y * inv);
        o1.z = f2bf(v1.z * inv); o1.w = f2bf(v1.w * inv);
        *(ushort4*)&sm[r * LROW + 4 * lane]       = o0;   // 8B LDS writes, stride-1: conflict-free
        *(ushort4*)&sm[r * LROW + 256 + 4 * lane] = o1;
    }
    __syncthreads();

    // coalesced write-out of the 16 KB packed group: thread t writes 16B at
    // out offset (p*256+t)*16; source = LDS row (t&15), k = kb*32 + q*8.
    char* outB = Epack + (size_t)blockIdx.x * 16384;
    const int r = tid & 15;
    const int q = (tid >> 4) & 3;
    #pragma unroll
    for (int p = 0; p < 4; p++) {
        const int kb = p * 4 + wave;                 // (p*256+t)>>6
        const int ks = kb * 32 + q * 8;
        ulonglong2 val = *(const ulonglong2*)&sm[r * LROW + ks]; // ds_read_b128, <=2-way conflict (free)
        *(ulonglong2*)(outB + (size_t)(p * 256 + tid) * 16) = val;
    }
}

// ---- kernel 2: upper-triangular 128x128 gram tiles, packed-global MFMA,
//      fused per-row min/max + last-block final mean ----
__global__ void __launch_bounds__(256, 2)
tl_gram(const char* __restrict__ Epack,
        const int* __restrict__ labels,
        unsigned* __restrict__ posArr,
        unsigned* __restrict__ negArr,
        unsigned* __restrict__ doneCnt,
        float* __restrict__ out) {
    __shared__ int rowLab[BT];
    __shared__ int colLab[BT];
    __shared__ int lastFlag;
    __shared__ float ssum[4];
    __shared__ int   scnt[4];

    // triangular decode: blockIdx.x -> (bi, bj) with bi <= bj
    int t = blockIdx.x, bi = 0, rowlen = NTILE;
    while (t >= rowlen) { t -= rowlen; rowlen--; bi++; }
    const int bj = bi + t;

    const int tid  = threadIdx.x;
    const int wave = tid >> 6;
    const int lane = tid & 63;
    const int quad = lane >> 4;
    const int l16  = lane & 15;
    const int wr   = wave >> 1;   // wave row (0..1): rows wr*64..+63
    const int wc   = wave & 1;    // wave col (0..1): cols wc*64..+63
    const int tileI = bi * BT;
    const int tileJ = bj * BT;
    const bool diag = (bi == bj);

    if (tid < BT) rowLab[tid] = labels[tileI + tid];
    else          colLab[tid - BT] = labels[tileJ + (tid - BT)];
    __syncthreads();   // labels visible for epilogue

    const char* aP[4];
    const char* bP[4];
    #pragma unroll
    for (int mi = 0; mi < 4; mi++)
        aP[mi] = Epack + (size_t)(tileI / 16 + wr * 4 + mi) * 16384 + (size_t)lane * 16;
    #pragma unroll
    for (int ni = 0; ni < 4; ni++)
        bP[ni] = Epack + (size_t)(tileJ / 16 + wc * 4 + ni) * 16384 + (size_t)lane * 16;

    f32x4 acc[4][4] = {};

    #pragma unroll
    for (int kc = 0; kc < KITERS; kc++) {
        bf16x8 a[4], b[4];
        #pragma unroll
        for (int mi = 0; mi < 4; mi++)
            a[mi] = *(const bf16x8*)(aP[mi] + kc * 1024);
        #pragma unroll
        for (int ni = 0; ni < 4; ni++)
            b[ni] = *(const bf16x8*)(bP[ni] + kc * 1024);

        #pragma unroll
        for (int mi = 0; mi < 4; mi++)
            #pragma unroll
            for (int ni = 0; ni < 4; ni++)
                acc[mi][ni] = __builtin_amdgcn_mfma_f32_16x16x32_bf16(
                    a[mi], b[ni], acc[mi][ni], 0, 0, 0);
    }

    // C/D layout: col = wc*64+ni*16+l16 (lane), row = wr*64+mi*16+quad*4+reg
    int rl[16], cl[4], clocv[4];
    #pragma unroll
    for (int mi = 0; mi < 4; mi++)
        #pragma unroll
        for (int reg = 0; reg < 4; reg++)
            rl[mi * 4 + reg] = rowLab[wr * 64 + mi * 16 + quad * 4 + reg];
    #pragma unroll
    for (int ni = 0; ni < 4; ni++) {
        clocv[ni] = wc * 64 + ni * 16 + l16;
        cl[ni] = colLab[clocv[ni]];
    }

    // ---- row pass ----
    #pragma unroll
    for (int mi = 0; mi < 4; mi++) {
        #pragma unroll
        for (int reg = 0; reg < 4; reg++) {
            const int rloc = wr * 64 + mi * 16 + quad * 4 + reg;
            const int lr   = rl[mi * 4 + reg];
            const int gi   = tileI + rloc;
            float pmin =  INFINITY;
            float nmax = -INFINITY;
            #pragma unroll
            for (int ni = 0; ni < 4; ni++) {
                const int gj  = tileJ + clocv[ni];
                const float g = acc[mi][ni][reg];
                const bool same = (lr == cl[ni]);
                if (same && gi != gj) pmin = fminf(pmin, g);
                if (!same)            nmax = fmaxf(nmax, g);
            }
            #pragma unroll
            for (int m = 1; m < 16; m <<= 1) {
                pmin = fminf(pmin, __shfl_xor(pmin, m));
                nmax = fmaxf(nmax, __shfl_xor(nmax, m));
            }
            if (l16 == 0) {
                if (pmin <  INFINITY) atomicMin(&posArr[gi], enc(pmin));
                if (nmax > -INFINITY) atomicMax(&negArr[gi], enc(nmax));
            }
        }
    }

    // ---- col pass (off-diag only) ----
    if (!diag) {
        #pragma unroll
        for (int ni = 0; ni < 4; ni++) {
            const int lc = cl[ni];
            const int gj = tileJ + clocv[ni];
            float pmin =  INFINITY;
            float nmax = -INFINITY;
            #pragma unroll
            for (int mi = 0; mi < 4; mi++) {
                #pragma unroll
                for (int reg = 0; reg < 4; reg++) {
                    const float g = acc[mi][ni][reg];
                    const bool same = (rl[mi * 4 + reg] == lc);
                    if (same) pmin = fminf(pmin, g);
                    else      nmax = fmaxf(nmax, g);
                }
            }
            pmin = fminf(pmin, __shfl_xor(pmin, 16));
            pmin = fminf(pmin, __shfl_xor(pmin, 32));
            nmax = fmaxf(nmax, __shfl_xor(nmax, 16));
            nmax = fmaxf(nmax, __shfl_xor(nmax, 32));
            if (quad == 0) {
                if (pmin <  INFINITY) atomicMin(&posArr[gj], enc(pmin));
                if (nmax > -INFINITY) atomicMax(&negArr[gj], enc(nmax));
            }
        }
    }

    // ---- completion: last block computes the final mean ----
    __threadfence();                       // release: our atomics visible
    if (tid == 0) {
        unsigned prev = atomicAdd(doneCnt, 1u);
        lastFlag = (prev == NPAIR - 1) ? 1 : 0;
    }
    __syncthreads();
    if (lastFlag) {
        __threadfence();
        float sum = 0.0f;
        int   count = 0;
        for (int i = tid; i < NROW; i += 256) {
            const unsigned pe = atomicOr(&posArr[i], 0u);  // device-coherent read
            const unsigned ne = atomicOr(&negArr[i], 0u);
            const bool valid = (pe != POS_INIT) && (ne != NEG_INIT);
            const float dap = sqrtf(fmaxf(2.0f - 2.0f * dec(pe), 0.0f));
            const float dan = sqrtf(fmaxf(2.0f - 2.0f * dec(ne), 0.0f));
            const float per = fmaxf(dap - dan + MARGIN, 0.0f);
            if (valid) { sum += per; count += 1; }
        }
        #pragma unroll
        for (int m = 32; m >= 1; m >>= 1) {
            sum   += __shfl_xor(sum, m);
            count += __shfl_xor(count, m);
        }
        if (lane == 0) { ssum[wave] = sum; scnt[wave] = count; }
        __syncthreads();
        if (tid == 0) {
            float s = ssum[0] + ssum[1] + ssum[2] + ssum[3];
            int   c = scnt[0] + scnt[1] + scnt[2] + scnt[3];
            out[0] = (c > 0) ? (s / (float)c) : 0.0f;
        }
    }
}

extern "C" void kernel_launch(void* const* d_in, const int* in_sizes, int n_in,
                              void* d_out, int out_size, void* d_ws, size_t ws_size,
                              hipStream_t stream) {
    const float* E      = (const float*)d_in[0];
    const int*   labels = (const int*)d_in[1];
    float*       out    = (float*)d_out;

    char* ws = (char*)d_ws;
    char* Epack           = ws;                                        // 4 MB packed
    unsigned* posArr      = (unsigned*)(ws + (size_t)NROW * DIM * 2);  // 16 KB
    unsigned* negArr      = posArr + NROW;                             // 16 KB
    unsigned* doneCnt     = negArr + NROW;                             // 4 B

    tl_norm<<<NROW / 16, 256, 0, stream>>>(E, Epack, posArr, negArr, doneCnt);
    tl_gram<<<NPAIR, 256, 0, stream>>>(Epack, labels, posArr, negArr, doneCnt, out);
}